// Round 1
// baseline (9495.098 us; speedup 1.0000x reference)
//
#include <hip/hip_runtime.h>

#define Tn 256
#define Bn 64
#define Xn 512
#define Hn 2048
#define Gn 8192  // 4*Hn

typedef short bf16x8 __attribute__((ext_vector_type(8)));
typedef float f32x4 __attribute__((ext_vector_type(4)));

static __device__ __forceinline__ unsigned short f2bf(float f) {
    unsigned int u = __builtin_bit_cast(unsigned int, f);
    u += 0x7fffu + ((u >> 16) & 1u);
    return (unsigned short)(u >> 16);
}
static __device__ __forceinline__ float bf2f(unsigned short s) {
    unsigned int u = ((unsigned int)s) << 16;
    return __builtin_bit_cast(float, u);
}
static __device__ __forceinline__ bf16x8 loadf8(const float* p) {
    float4 u = *(const float4*)p;
    float4 v = *(const float4*)(p + 4);
    bf16x8 r;
    r[0] = (short)f2bf(u.x); r[1] = (short)f2bf(u.y);
    r[2] = (short)f2bf(u.z); r[3] = (short)f2bf(u.w);
    r[4] = (short)f2bf(v.x); r[5] = (short)f2bf(v.y);
    r[6] = (short)f2bf(v.z); r[7] = (short)f2bf(v.w);
    return r;
}
static __device__ __forceinline__ void cvt4(const float* __restrict__ s,
                                            unsigned short* __restrict__ d, int i) {
    float4 v = ((const float4*)s)[i];
    ushort4 o;
    o.x = f2bf(v.x); o.y = f2bf(v.y); o.z = f2bf(v.z); o.w = f2bf(v.w);
    ((ushort4*)d)[i] = o;
}
static __device__ __forceinline__ float sigm(float x) {
    return 1.f / (1.f + __expf(-x));
}
static __device__ __forceinline__ float ftanh(float x) {
    float e = __expf(2.f * x);
    return (e - 1.f) / (e + 1.f);
}

// ---------------- convert kernels ----------------
__global__ void convert_full(const float* __restrict__ w_hh, const float* __restrict__ w_ih,
                             const float* __restrict__ x, const float* __restrict__ b_ih,
                             const float* __restrict__ b_hh, const float* __restrict__ h0,
                             const float* __restrict__ c0,
                             unsigned short* __restrict__ Whh, unsigned short* __restrict__ Wih,
                             unsigned short* __restrict__ Xb, float* __restrict__ bias,
                             unsigned short* __restrict__ hbf0, float* __restrict__ cbuf)
{
    int i = blockIdx.x * blockDim.x + threadIdx.x;   // float4-granularity index
    const int n_whh = Gn * Hn / 4;   // 4194304
    const int n_wih = Gn * Xn / 4;   // 1048576
    const int n_x   = Tn * Bn * Xn / 4; // 2097152
    const int n_h   = Bn * Hn / 4;   // 32768
    const int n_b   = Gn / 4;        // 2048
    if (i < n_whh) { cvt4(w_hh, Whh, i); return; }
    i -= n_whh;
    if (i < n_wih) { cvt4(w_ih, Wih, i); return; }
    i -= n_wih;
    if (i < n_x)   { cvt4(x, Xb, i); return; }
    i -= n_x;
    if (i < n_h)   { cvt4(h0, hbf0, i); return; }
    i -= n_h;
    if (i < n_h)   { ((float4*)cbuf)[i] = ((const float4*)c0)[i]; return; }
    i -= n_h;
    if (i < n_b) {
        float4 a = ((const float4*)b_ih)[i];
        float4 b = ((const float4*)b_hh)[i];
        ((float4*)bias)[i] = make_float4(a.x + b.x, a.y + b.y, a.z + b.z, a.w + b.w);
    }
}

__global__ void convert_small(const float* __restrict__ h0, const float* __restrict__ c0,
                              unsigned short* __restrict__ hbf0, float* __restrict__ cbuf)
{
    int i = blockIdx.x * blockDim.x + threadIdx.x;
    const int n_h = Bn * Hn / 4;
    if (i < n_h) { cvt4(h0, hbf0, i); return; }
    i -= n_h;
    if (i < n_h) { ((float4*)cbuf)[i] = ((const float4*)c0)[i]; }
}

// ---------------- softmax helper ----------------
static __device__ __forceinline__ void softmax_row(const unsigned short* __restrict__ hr,
                                                   float* __restrict__ yr, int lane) {
    float v[32];
    float m = -1e30f;
    #pragma unroll
    for (int i = 0; i < 32; ++i) { v[i] = bf2f(hr[lane + (i << 6)]); m = fmaxf(m, v[i]); }
    #pragma unroll
    for (int off = 32; off; off >>= 1) m = fmaxf(m, __shfl_xor(m, off));
    float s = 0.f;
    #pragma unroll
    for (int i = 0; i < 32; ++i) { v[i] = __expf(v[i] - m); s += v[i]; }
    #pragma unroll
    for (int off = 32; off; off >>= 1) s += __shfl_xor(s, off);
    float inv = 1.f / s;
    #pragma unroll
    for (int i = 0; i < 32; ++i) yr[lane + (i << 6)] = v[i] * inv;
}

__global__ __launch_bounds__(64) void softmax_final(const unsigned short* __restrict__ h,
                                                    float* __restrict__ ys) {
    softmax_row(h + (size_t)blockIdx.x * Hn, ys + (size_t)blockIdx.x * Hn, threadIdx.x);
}

// ---------------- fused step kernel ----------------
#define MFMA8() \
    acc[0][0] = __builtin_amdgcn_mfma_f32_16x16x32_bf16(a0, b0, acc[0][0], 0, 0, 0); \
    acc[1][0] = __builtin_amdgcn_mfma_f32_16x16x32_bf16(a1, b0, acc[1][0], 0, 0, 0); \
    acc[0][1] = __builtin_amdgcn_mfma_f32_16x16x32_bf16(a0, b1, acc[0][1], 0, 0, 0); \
    acc[1][1] = __builtin_amdgcn_mfma_f32_16x16x32_bf16(a1, b1, acc[1][1], 0, 0, 0); \
    acc[0][2] = __builtin_amdgcn_mfma_f32_16x16x32_bf16(a0, b2, acc[0][2], 0, 0, 0); \
    acc[1][2] = __builtin_amdgcn_mfma_f32_16x16x32_bf16(a1, b2, acc[1][2], 0, 0, 0); \
    acc[0][3] = __builtin_amdgcn_mfma_f32_16x16x32_bf16(a0, b3, acc[0][3], 0, 0, 0); \
    acc[1][3] = __builtin_amdgcn_mfma_f32_16x16x32_bf16(a1, b3, acc[1][3], 0, 0, 0);

template <int MODE>   // 0: weights/x preconverted bf16; 1: fp32 direct with inline convert
__global__ __launch_bounds__(64) void lstm_step(
    const void* __restrict__ WhhP, const void* __restrict__ WihP,
    const void* __restrict__ XtP, const float* __restrict__ biasP,
    const float* __restrict__ b_ih, const float* __restrict__ b_hh,
    const unsigned short* __restrict__ hprev, unsigned short* __restrict__ hcur,
    float* __restrict__ cbuf, float* __restrict__ ys_prev, float* __restrict__ hT)
{
    int w = blockIdx.x;
    int lane = threadIdx.x;

    if (w >= 256) {
        // fused softmax of h_t (=hprev) -> ys[t-1]
        if (!ys_prev) return;
        int b = w - 256;
        softmax_row(hprev + (size_t)b * Hn, ys_prev + (size_t)b * Hn, lane);
        return;
    }

    int cg = w & 127;            // column group: units j0..j0+15
    int rh = w >> 7;             // row half: rows rb..rb+31
    int j0 = cg << 4;
    int rb = rh << 5;
    int lm = lane & 15, lh = lane >> 4;

    f32x4 acc[2][4];
    #pragma unroll
    for (int g = 0; g < 4; ++g) {
        float bv;
        if constexpr (MODE == 0) bv = biasP[g * Hn + j0 + lm];
        else                     bv = b_ih[g * Hn + j0 + lm] + b_hh[g * Hn + j0 + lm];
        acc[0][g] = (f32x4){bv, bv, bv, bv};
        acc[1][g] = acc[0][g];
    }

    // ---- h part: K = 2048 ----
    {
        const int rsu = Hn / 8;  // row stride in bf16x8 units = 256
        const bf16x8* A0 = (const bf16x8*)hprev + (rb + lm) * rsu + lh;
        const bf16x8* A1 = A0 + 16 * rsu;
        if constexpr (MODE == 0) {
            const bf16x8* Wb = (const bf16x8*)WhhP;
            const bf16x8* B0 = Wb + (0 * Hn + j0 + lm) * rsu + lh;
            const bf16x8* B1 = Wb + (1 * Hn + j0 + lm) * rsu + lh;
            const bf16x8* B2 = Wb + (2 * Hn + j0 + lm) * rsu + lh;
            const bf16x8* B3 = Wb + (3 * Hn + j0 + lm) * rsu + lh;
            bf16x8 a0 = A0[0], a1 = A1[0];
            bf16x8 b0 = B0[0], b1 = B1[0], b2 = B2[0], b3 = B3[0];
            for (int k = 1; k < Hn / 32; ++k) {
                bf16x8 na0 = A0[k * 4], na1 = A1[k * 4];
                bf16x8 nb0 = B0[k * 4], nb1 = B1[k * 4], nb2 = B2[k * 4], nb3 = B3[k * 4];
                MFMA8();
                a0 = na0; a1 = na1; b0 = nb0; b1 = nb1; b2 = nb2; b3 = nb3;
            }
            MFMA8();
        } else {
            const float* Wf = (const float*)WhhP;
            for (int k = 0; k < Hn / 32; ++k) {
                int kb = k * 32 + lh * 8;
                bf16x8 a0 = A0[k * 4], a1 = A1[k * 4];
                bf16x8 b0 = loadf8(Wf + (size_t)(0 * Hn + j0 + lm) * Hn + kb);
                bf16x8 b1 = loadf8(Wf + (size_t)(1 * Hn + j0 + lm) * Hn + kb);
                bf16x8 b2 = loadf8(Wf + (size_t)(2 * Hn + j0 + lm) * Hn + kb);
                bf16x8 b3 = loadf8(Wf + (size_t)(3 * Hn + j0 + lm) * Hn + kb);
                MFMA8();
            }
        }
    }

    // ---- x part: K = 512 ----
    {
        if constexpr (MODE == 0) {
            const int rsu = Xn / 8;  // 64
            const bf16x8* A0 = (const bf16x8*)XtP + (rb + lm) * rsu + lh;
            const bf16x8* A1 = A0 + 16 * rsu;
            const bf16x8* Wb = (const bf16x8*)WihP;
            const bf16x8* B0 = Wb + (0 * Hn + j0 + lm) * rsu + lh;
            const bf16x8* B1 = Wb + (1 * Hn + j0 + lm) * rsu + lh;
            const bf16x8* B2 = Wb + (2 * Hn + j0 + lm) * rsu + lh;
            const bf16x8* B3 = Wb + (3 * Hn + j0 + lm) * rsu + lh;
            for (int k = 0; k < Xn / 32; ++k) {
                bf16x8 a0 = A0[k * 4], a1 = A1[k * 4];
                bf16x8 b0 = B0[k * 4], b1 = B1[k * 4], b2 = B2[k * 4], b3 = B3[k * 4];
                MFMA8();
            }
        } else {
            const float* Xf = (const float*)XtP;
            const float* Wf = (const float*)WihP;
            for (int k = 0; k < Xn / 32; ++k) {
                int kb = k * 32 + lh * 8;
                bf16x8 a0 = loadf8(Xf + (size_t)(rb + lm) * Xn + kb);
                bf16x8 a1 = loadf8(Xf + (size_t)(rb + 16 + lm) * Xn + kb);
                bf16x8 b0 = loadf8(Wf + (size_t)(0 * Hn + j0 + lm) * Xn + kb);
                bf16x8 b1 = loadf8(Wf + (size_t)(1 * Hn + j0 + lm) * Xn + kb);
                bf16x8 b2 = loadf8(Wf + (size_t)(2 * Hn + j0 + lm) * Xn + kb);
                bf16x8 b3 = loadf8(Wf + (size_t)(3 * Hn + j0 + lm) * Xn + kb);
                MFMA8();
            }
        }
    }

    // ---- LSTM cell, fused (gate order: i, f, g, o) ----
    const int col = j0 + lm;
    #pragma unroll
    for (int rt = 0; rt < 2; ++rt) {
        #pragma unroll
        for (int r = 0; r < 4; ++r) {
            int row = rb + rt * 16 + lh * 4 + r;   // batch index
            size_t off = (size_t)row * Hn + col;
            float iv = sigm(acc[rt][0][r]);
            float fv = sigm(acc[rt][1][r]);
            float gv = ftanh(acc[rt][2][r]);
            float ov = sigm(acc[rt][3][r]);
            float cp = cbuf[off];
            float cn = fv * cp + iv * gv;
            float hn = ov * ftanh(cn);
            cbuf[off] = cn;
            hcur[off] = f2bf(hn);
            if (hT) hT[off] = hn;
        }
    }
}

// ---------------- host ----------------
extern "C" void kernel_launch(void* const* d_in, const int* in_sizes, int n_in,
                              void* d_out, int out_size, void* d_ws, size_t ws_size,
                              hipStream_t stream) {
    const float* input = (const float*)d_in[0];
    const float* h0    = (const float*)d_in[1];
    const float* c0    = (const float*)d_in[2];
    const float* w_ih  = (const float*)d_in[3];
    const float* w_hh  = (const float*)d_in[4];
    const float* b_ih  = (const float*)d_in[5];
    const float* b_hh  = (const float*)d_in[6];

    float* ys   = (float*)d_out;                       // [256][64][2048]
    float* hT   = ys + (size_t)Tn * Bn * Hn;           // [64][2048]
    float* cbuf = hT + (size_t)Bn * Hn;                // c_T slot doubles as live c

    char* wsb = (char*)d_ws;
    const size_t off_whh  = 0;
    const size_t off_wih  = off_whh + (size_t)Gn * Hn * 2;      // 33,554,432
    const size_t off_x    = off_wih + (size_t)Gn * Xn * 2;      // 41,943,040
    const size_t off_bias = off_x + (size_t)Tn * Bn * Xn * 2;   // 58,720,256
    const size_t off_h0   = off_bias + (size_t)Gn * 4;          // 58,753,024
    const size_t off_h1   = off_h0 + (size_t)Bn * Hn * 2;       // 59,015,168
    const size_t need     = off_h1 + (size_t)Bn * Hn * 2;       // 59,277,312

    const bool mode0 = (ws_size >= need);

    unsigned short* hbf[2];
    if (mode0) {
        hbf[0] = (unsigned short*)(wsb + off_h0);
        hbf[1] = (unsigned short*)(wsb + off_h1);
    } else {
        hbf[0] = (unsigned short*)wsb;
        hbf[1] = (unsigned short*)(wsb + (size_t)Bn * Hn * 2);
    }

    if (mode0) {
        unsigned short* Whh = (unsigned short*)(wsb + off_whh);
        unsigned short* Wih = (unsigned short*)(wsb + off_wih);
        unsigned short* Xb  = (unsigned short*)(wsb + off_x);
        float* bias = (float*)(wsb + off_bias);
        convert_full<<<dim3(28936), dim3(256), 0, stream>>>(
            w_hh, w_ih, input, b_ih, b_hh, h0, c0, Whh, Wih, Xb, bias, hbf[0], cbuf);
        for (int t = 0; t < Tn; ++t) {
            lstm_step<0><<<dim3(320), dim3(64), 0, stream>>>(
                Whh, Wih, Xb + (size_t)t * Bn * Xn, bias, nullptr, nullptr,
                hbf[t & 1], hbf[(t + 1) & 1], cbuf,
                t ? ys + (size_t)(t - 1) * Bn * Hn : nullptr,
                (t == Tn - 1) ? hT : nullptr);
        }
    } else {
        convert_small<<<dim3(256), dim3(256), 0, stream>>>(h0, c0, hbf[0], cbuf);
        for (int t = 0; t < Tn; ++t) {
            lstm_step<1><<<dim3(320), dim3(64), 0, stream>>>(
                w_hh, w_ih, input + (size_t)t * Bn * Xn, nullptr, b_ih, b_hh,
                hbf[t & 1], hbf[(t + 1) & 1], cbuf,
                t ? ys + (size_t)(t - 1) * Bn * Hn : nullptr,
                (t == Tn - 1) ? hT : nullptr);
        }
    }
    softmax_final<<<dim3(Bn), dim3(64), 0, stream>>>(hbf[Tn & 1], ys + (size_t)(Tn - 1) * Bn * Hn);
}

// Round 4
// 4283.442 us; speedup vs baseline: 2.2167x; 2.2167x over previous
//
#include <hip/hip_runtime.h>

#define Tn 256
#define Bn 64
#define Xn 512
#define Hn 2048
#define Gn 8192  // 4*Hn
#define NWG 256

typedef short bf16x8 __attribute__((ext_vector_type(8)));
typedef float f32x4 __attribute__((ext_vector_type(4)));

static __device__ __forceinline__ unsigned short f2bf(float f) {
    unsigned int u = __builtin_bit_cast(unsigned int, f);
    u += 0x7fffu + ((u >> 16) & 1u);
    return (unsigned short)(u >> 16);
}
static __device__ __forceinline__ float bf2f(unsigned short s) {
    unsigned int u = ((unsigned int)s) << 16;
    return __builtin_bit_cast(float, u);
}
static __device__ __forceinline__ void cvt4(const float* __restrict__ s,
                                            unsigned short* __restrict__ d, int i) {
    float4 v = ((const float4*)s)[i];
    ushort4 o;
    o.x = f2bf(v.x); o.y = f2bf(v.y); o.z = f2bf(v.z); o.w = f2bf(v.w);
    ((ushort4*)d)[i] = o;
}
static __device__ __forceinline__ float sigm(float x) {
    return 1.f / (1.f + __expf(-x));
}
static __device__ __forceinline__ float ftanh(float x) {
    float e = __expf(2.f * x);
    return (e - 1.f) / (e + 1.f);
}

// ---------------- grid barrier (sharded arrive, gen poll) ----------------
// bar layout (unsigned words): shard counters at i*32 (i=0..7), super at 256, gen at 288.
static __device__ __forceinline__ void bar_wait(unsigned* bar, unsigned t) {
    if (t) {
        while (__hip_atomic_load(bar + 288, __ATOMIC_RELAXED, __HIP_MEMORY_SCOPE_AGENT) < t)
            __builtin_amdgcn_s_sleep(2);
    }
    __builtin_amdgcn_fence(__ATOMIC_ACQUIRE, "agent");
}
static __device__ __forceinline__ void bar_arrive(unsigned* bar, int wg, unsigned t) {
    __builtin_amdgcn_fence(__ATOMIC_RELEASE, "agent");
    unsigned* shard = bar + (wg >> 5) * 32;
    unsigned n = __hip_atomic_fetch_add(shard, 1u, __ATOMIC_RELAXED, __HIP_MEMORY_SCOPE_AGENT);
    if (n == 31u) {
        __hip_atomic_store(shard, 0u, __ATOMIC_RELAXED, __HIP_MEMORY_SCOPE_AGENT);
        unsigned m = __hip_atomic_fetch_add(bar + 256, 1u, __ATOMIC_RELAXED, __HIP_MEMORY_SCOPE_AGENT);
        if (m == 7u) {
            __hip_atomic_store(bar + 256, 0u, __ATOMIC_RELAXED, __HIP_MEMORY_SCOPE_AGENT);
            __hip_atomic_store(bar + 288, t + 1u, __ATOMIC_RELEASE, __HIP_MEMORY_SCOPE_AGENT);
        }
    }
}

// ---------------- softmax helpers ----------------
static __device__ __forceinline__ void softmax_row(const unsigned short* __restrict__ hr,
                                                   float* __restrict__ yr, int lane) {
    float v[32];
    float m = -1e30f;
    #pragma unroll
    for (int i = 0; i < 32; ++i) { v[i] = bf2f(hr[lane + (i << 6)]); m = fmaxf(m, v[i]); }
    #pragma unroll
    for (int off = 32; off; off >>= 1) m = fmaxf(m, __shfl_xor(m, off));
    float s = 0.f;
    #pragma unroll
    for (int i = 0; i < 32; ++i) { v[i] = __expf(v[i] - m); s += v[i]; }
    #pragma unroll
    for (int off = 32; off; off >>= 1) s += __shfl_xor(s, off);
    float inv = 1.f / s;
    #pragma unroll
    for (int i = 0; i < 32; ++i) yr[lane + (i << 6)] = v[i] * inv;
}

// blocked h layout: elem(row,unit) at ((unit>>3)*64 + row)*8 + (unit&7)
static __device__ __forceinline__ void softmax_row_blocked(const unsigned short* __restrict__ hb,
                                                           int row, float* __restrict__ yr, int lane) {
    float v[32];
    float m = -1e30f;
    #pragma unroll
    for (int i = 0; i < 32; ++i) {
        int unit = (i << 6) + lane;
        v[i] = bf2f(hb[(((unit >> 3) << 6) + row) * 8 + (unit & 7)]);
        m = fmaxf(m, v[i]);
    }
    #pragma unroll
    for (int off = 32; off; off >>= 1) m = fmaxf(m, __shfl_xor(m, off));
    float s = 0.f;
    #pragma unroll
    for (int i = 0; i < 32; ++i) { v[i] = __expf(v[i] - m); s += v[i]; }
    #pragma unroll
    for (int off = 32; off; off >>= 1) s += __shfl_xor(s, off);
    float inv = 1.f / s;
    #pragma unroll
    for (int i = 0; i < 32; ++i) yr[lane + (i << 6)] = v[i] * inv;
}

// ---------------- prologue for persistent path ----------------
__global__ void prologue_coop(const float* __restrict__ x, const float* __restrict__ h0,
                              const float* __restrict__ b_ih, const float* __restrict__ b_hh,
                              unsigned short* __restrict__ Xb, unsigned short* __restrict__ hb0,
                              float* __restrict__ bias, unsigned* __restrict__ bar)
{
    int i = blockIdx.x * blockDim.x + threadIdx.x;
    const int n_x = Tn * Bn * Xn / 4;  // 2097152
    const int n_h = Bn * Hn / 4;       // 32768
    const int n_b = Gn / 4;            // 2048
    if (i < n_x) { cvt4(x, Xb, i); return; }
    i -= n_x;
    if (i < n_h) {
        // h0 -> blocked bf16 layout
        int flat = i * 4;
        int row = flat >> 11, unit0 = flat & 2047;
        float4 v = ((const float4*)h0)[i];
        ushort4 o;
        o.x = f2bf(v.x); o.y = f2bf(v.y); o.z = f2bf(v.z); o.w = f2bf(v.w);
        int dst = (((unit0 >> 3) << 6) + row) * 8 + (unit0 & 7);
        *(ushort4*)(hb0 + dst) = o;
        return;
    }
    i -= n_h;
    if (i < n_b) {
        float4 a = ((const float4*)b_ih)[i];
        float4 b = ((const float4*)b_hh)[i];
        ((float4*)bias)[i] = make_float4(a.x + b.x, a.y + b.y, a.z + b.z, a.w + b.w);
        return;
    }
    i -= n_b;
    if (i < 320) bar[i] = 0u;
}

// ---------------- persistent LSTM kernel ----------------
#define MFMA2() \
    acc0 = __builtin_amdgcn_mfma_f32_16x16x32_bf16(a, b0, acc0, 0, 0, 0); \
    acc1 = __builtin_amdgcn_mfma_f32_16x16x32_bf16(a, b1, acc1, 0, 0, 0);

__global__ __launch_bounds__(320, 1) void lstm_persist(
    const unsigned short* __restrict__ Xb, const float* __restrict__ bias,
    const float* __restrict__ c0,
    unsigned short* __restrict__ hb0, unsigned short* __restrict__ hb1,
    const float* __restrict__ w_hh, const float* __restrict__ w_ih,
    float* __restrict__ ys, float* __restrict__ hT, float* __restrict__ cT,
    unsigned* __restrict__ bar)
{
    extern __shared__ char smem[];
    const unsigned short* LW = (const unsigned short*)smem;             // Whh frags 128KB
    const unsigned short* LX = (const unsigned short*)(smem + 131072);  // Wih frags 32KB

    const int wg  = blockIdx.x;
    const int tid = threadIdx.x;
    const int U0  = wg * 8;

    // ---- stage weight slices into LDS as B-fragments (all 5 waves help) ----
    for (int i = tid; i < 32 * 512; i += 320) {
        int c = i >> 9, k = (i & 511) * 4;
        int g = c >> 3, u = c & 7;
        float4 v = *(const float4*)(w_hh + (size_t)(g * Hn + U0 + u) * Hn + k);
        ushort4 o;
        o.x = f2bf(v.x); o.y = f2bf(v.y); o.z = f2bf(v.z); o.w = f2bf(v.w);
        int ct = c >> 4, kk = k >> 5, l = ((k >> 3) & 3) * 16 + (c & 15);
        *(ushort4*)(smem + ((size_t)((ct * 64 + kk) * 64 + l) * 16 + (k & 7) * 2)) = o;
    }
    for (int i = tid; i < 32 * 128; i += 320) {
        int c = i >> 7, k = (i & 127) * 4;
        int g = c >> 3, u = c & 7;
        float4 v = *(const float4*)(w_ih + (size_t)(g * Hn + U0 + u) * Xn + k);
        ushort4 o;
        o.x = f2bf(v.x); o.y = f2bf(v.y); o.z = f2bf(v.z); o.w = f2bf(v.w);
        int ct = c >> 4, kk = k >> 5, l = ((k >> 3) & 3) * 16 + (c & 15);
        *(ushort4*)(smem + (131072 + (size_t)((ct * 16 + kk) * 64 + l) * 16 + (k & 7) * 2)) = o;
    }
    __syncthreads();

    const int w = tid >> 6, l = tid & 63;
    const int lm = l & 15, lh = l >> 4;

    // per-lane cell mapping (waves 0..3)
    const int row0 = w * 16;
    const int u  = lm & 7;
    const bool hi = (lm & 8) != 0;
    const int r0g = row0 + 4 * lh + (hi ? 2 : 0);   // global batch rows r0g, r0g+1

    float bi = 0.f, bf_ = 0.f, bg = 0.f, bo = 0.f, cs0 = 0.f, cs1 = 0.f;
    if (w < 4) {
        bi  = bias[0 * Hn + U0 + u];
        bf_ = bias[1 * Hn + U0 + u];
        bg  = bias[2 * Hn + U0 + u];
        bo  = bias[3 * Hn + U0 + u];
        cs0 = c0[(size_t)r0g * Hn + U0 + u];
        cs1 = c0[(size_t)(r0g + 1) * Hn + U0 + u];
    }

    for (int t = 0; t < Tn; ++t) {
        const unsigned short* hb = (t & 1) ? hb1 : hb0;
        unsigned short* hn = (t & 1) ? hb0 : hb1;

        f32x4 acc0 = {0.f, 0.f, 0.f, 0.f}, acc1 = {0.f, 0.f, 0.f, 0.f};

        if (w < 4) {
            // ---- x-part (K=512), independent of h(t): overlaps barrier wait ----
            const unsigned short* xa = Xb + ((size_t)(t * 64 + row0 + lm) * Xn) + lh * 8;
            bf16x8 aP[4];
            #pragma unroll
            for (int j = 0; j < 4; ++j) aP[j] = *(const bf16x8*)(xa + j * 32);
            #pragma unroll 4
            for (int kk = 0; kk < 16; ++kk) {
                bf16x8 a = aP[kk & 3];
                if (kk < 12) aP[kk & 3] = *(const bf16x8*)(xa + (kk + 4) * 32);
                bf16x8 b0 = *(const bf16x8*)(LX + ((size_t)((0 * 16 + kk) * 64 + l) << 3));
                bf16x8 b1 = *(const bf16x8*)(LX + ((size_t)((1 * 16 + kk) * 64 + l) << 3));
                MFMA2();
            }
        }

        if (tid == 0) bar_wait(bar, (unsigned)t);
        __syncthreads();

        if (w < 4) {
            // ---- h-part (K=2048), blocked-h A loads ----
            const unsigned short* ha = hb + (size_t)(row0 + lm) * 8;
            bf16x8 aP[4];
            #pragma unroll
            for (int j = 0; j < 4; ++j)
                aP[j] = *(const bf16x8*)(ha + (size_t)((j * 4 + lh) << 6) * 8);
            #pragma unroll 4
            for (int kk = 0; kk < 64; ++kk) {
                bf16x8 a = aP[kk & 3];
                if (kk < 60)
                    aP[kk & 3] = *(const bf16x8*)(ha + (size_t)((((kk + 4) * 4 + lh)) << 6) * 8);
                bf16x8 b0 = *(const bf16x8*)(LW + ((size_t)((0 * 64 + kk) * 64 + l) << 3));
                bf16x8 b1 = *(const bf16x8*)(LW + ((size_t)((1 * 64 + kk) * 64 + l) << 3));
                MFMA2();
            }

            // ---- cell: exchange gate pairs across lane^8, update c in regs ----
            f32x4 s0, s1;
            #pragma unroll
            for (int r = 0; r < 4; ++r) { s0[r] = __shfl_xor(acc0[r], 8); s1[r] = __shfl_xor(acc1[r], 8); }
            #pragma unroll
            for (int j = 0; j < 2; ++j) {
                int r = (hi ? 2 : 0) + j;
                float gi = (hi ? s0[r] : acc0[r]) + bi;
                float gf = (hi ? acc0[r] : s0[r]) + bf_;
                float gg = (hi ? s1[r] : acc1[r]) + bg;
                float go = (hi ? acc1[r] : s1[r]) + bo;
                float iv = sigm(gi), fv = sigm(gf), gv = ftanh(gg), ov = sigm(go);
                float cc = j ? cs1 : cs0;
                float cn = fv * cc + iv * gv;
                float hv = ov * ftanh(cn);
                if (j) cs1 = cn; else cs0 = cn;
                int rowg = r0g + j;
                hn[(size_t)wg * 512 + rowg * 8 + u] = f2bf(hv);     // private blocked region
                if (t == Tn - 1) {
                    size_t off = (size_t)rowg * Hn + U0 + u;
                    hT[off] = hv;
                    cT[off] = cn;
                }
            }
        } else if (wg < 64 && t > 0) {
            // wave 4: softmax of h(t) -> ys[t-1], overlapped with GEMM
            softmax_row_blocked(hb, wg, ys + ((size_t)(t - 1) * Bn + wg) * Hn, l);
        }

        __syncthreads();
        if (tid == 0) bar_arrive(bar, wg, (unsigned)t);
    }

    if (tid == 0) bar_wait(bar, Tn);
    __syncthreads();
    if (w == 4 && wg < 64)
        softmax_row_blocked(hb0, wg, ys + ((size_t)(Tn - 1) * Bn + wg) * Hn, l);
}

// =======================================================================
// ---------------- round-1 fallback path (kept verbatim) ----------------
// =======================================================================
__global__ void convert_full(const float* __restrict__ w_hh, const float* __restrict__ w_ih,
                             const float* __restrict__ x, const float* __restrict__ b_ih,
                             const float* __restrict__ b_hh, const float* __restrict__ h0,
                             const float* __restrict__ c0,
                             unsigned short* __restrict__ Whh, unsigned short* __restrict__ Wih,
                             unsigned short* __restrict__ Xb, float* __restrict__ bias,
                             unsigned short* __restrict__ hbf0, float* __restrict__ cbuf)
{
    int i = blockIdx.x * blockDim.x + threadIdx.x;
    const int n_whh = Gn * Hn / 4;
    const int n_wih = Gn * Xn / 4;
    const int n_x   = Tn * Bn * Xn / 4;
    const int n_h   = Bn * Hn / 4;
    const int n_b   = Gn / 4;
    if (i < n_whh) { cvt4(w_hh, Whh, i); return; }
    i -= n_whh;
    if (i < n_wih) { cvt4(w_ih, Wih, i); return; }
    i -= n_wih;
    if (i < n_x)   { cvt4(x, Xb, i); return; }
    i -= n_x;
    if (i < n_h)   { cvt4(h0, hbf0, i); return; }
    i -= n_h;
    if (i < n_h)   { ((float4*)cbuf)[i] = ((const float4*)c0)[i]; return; }
    i -= n_h;
    if (i < n_b) {
        float4 a = ((const float4*)b_ih)[i];
        float4 b = ((const float4*)b_hh)[i];
        ((float4*)bias)[i] = make_float4(a.x + b.x, a.y + b.y, a.z + b.z, a.w + b.w);
    }
}

__global__ __launch_bounds__(64) void softmax_final(const unsigned short* __restrict__ h,
                                                    float* __restrict__ ys) {
    softmax_row(h + (size_t)blockIdx.x * Hn, ys + (size_t)blockIdx.x * Hn, threadIdx.x);
}

#define MFMA8() \
    acc[0][0] = __builtin_amdgcn_mfma_f32_16x16x32_bf16(a0, b0, acc[0][0], 0, 0, 0); \
    acc[1][0] = __builtin_amdgcn_mfma_f32_16x16x32_bf16(a1, b0, acc[1][0], 0, 0, 0); \
    acc[0][1] = __builtin_amdgcn_mfma_f32_16x16x32_bf16(a0, b1, acc[0][1], 0, 0, 0); \
    acc[1][1] = __builtin_amdgcn_mfma_f32_16x16x32_bf16(a1, b1, acc[1][1], 0, 0, 0); \
    acc[0][2] = __builtin_amdgcn_mfma_f32_16x16x32_bf16(a0, b2, acc[0][2], 0, 0, 0); \
    acc[1][2] = __builtin_amdgcn_mfma_f32_16x16x32_bf16(a1, b2, acc[1][2], 0, 0, 0); \
    acc[0][3] = __builtin_amdgcn_mfma_f32_16x16x32_bf16(a0, b3, acc[0][3], 0, 0, 0); \
    acc[1][3] = __builtin_amdgcn_mfma_f32_16x16x32_bf16(a1, b3, acc[1][3], 0, 0, 0);

__global__ __launch_bounds__(64) void lstm_step(
    const void* __restrict__ WhhP, const void* __restrict__ WihP,
    const void* __restrict__ XtP, const float* __restrict__ biasP,
    const unsigned short* __restrict__ hprev, unsigned short* __restrict__ hcur,
    float* __restrict__ cbuf, float* __restrict__ ys_prev, float* __restrict__ hT)
{
    int w = blockIdx.x;
    int lane = threadIdx.x;
    if (w >= 256) {
        if (!ys_prev) return;
        int b = w - 256;
        softmax_row(hprev + (size_t)b * Hn, ys_prev + (size_t)b * Hn, lane);
        return;
    }
    int cg = w & 127, rh = w >> 7;
    int j0 = cg << 4, rb = rh << 5;
    int lm = lane & 15, lh = lane >> 4;
    f32x4 acc[2][4];
    #pragma unroll
    for (int g = 0; g < 4; ++g) {
        float bv = biasP[g * Hn + j0 + lm];
        acc[0][g] = (f32x4){bv, bv, bv, bv};
        acc[1][g] = acc[0][g];
    }
    {
        const int rsu = Hn / 8;
        const bf16x8* A0 = (const bf16x8*)hprev + (rb + lm) * rsu + lh;
        const bf16x8* A1 = A0 + 16 * rsu;
        const bf16x8* Wb = (const bf16x8*)WhhP;
        const bf16x8* B0 = Wb + (0 * Hn + j0 + lm) * rsu + lh;
        const bf16x8* B1 = Wb + (1 * Hn + j0 + lm) * rsu + lh;
        const bf16x8* B2 = Wb + (2 * Hn + j0 + lm) * rsu + lh;
        const bf16x8* B3 = Wb + (3 * Hn + j0 + lm) * rsu + lh;
        bf16x8 a0 = A0[0], a1 = A1[0];
        bf16x8 b0 = B0[0], b1 = B1[0], b2 = B2[0], b3 = B3[0];
        for (int k = 1; k < Hn / 32; ++k) {
            bf16x8 na0 = A0[k * 4], na1 = A1[k * 4];
            bf16x8 nb0 = B0[k * 4], nb1 = B1[k * 4], nb2 = B2[k * 4], nb3 = B3[k * 4];
            MFMA8();
            a0 = na0; a1 = na1; b0 = nb0; b1 = nb1; b2 = nb2; b3 = nb3;
        }
        MFMA8();
    }
    {
        const int rsu = Xn / 8;
        const bf16x8* A0 = (const bf16x8*)XtP + (rb + lm) * rsu + lh;
        const bf16x8* A1 = A0 + 16 * rsu;
        const bf16x8* Wb = (const bf16x8*)WihP;
        const bf16x8* B0 = Wb + (0 * Hn + j0 + lm) * rsu + lh;
        const bf16x8* B1 = Wb + (1 * Hn + j0 + lm) * rsu + lh;
        const bf16x8* B2 = Wb + (2 * Hn + j0 + lm) * rsu + lh;
        const bf16x8* B3 = Wb + (3 * Hn + j0 + lm) * rsu + lh;
        for (int k = 0; k < Xn / 32; ++k) {
            bf16x8 a0 = A0[k * 4], a1 = A1[k * 4];
            bf16x8 b0 = B0[k * 4], b1 = B1[k * 4], b2 = B2[k * 4], b3 = B3[k * 4];
            MFMA8();
        }
    }
    const int col = j0 + lm;
    #pragma unroll
    for (int rt = 0; rt < 2; ++rt) {
        #pragma unroll
        for (int r = 0; r < 4; ++r) {
            int row = rb + rt * 16 + lh * 4 + r;
            size_t off = (size_t)row * Hn + col;
            float iv = sigm(acc[rt][0][r]);
            float fv = sigm(acc[rt][1][r]);
            float gv = ftanh(acc[rt][2][r]);
            float ov = sigm(acc[rt][3][r]);
            float cp = cbuf[off];
            float cn = fv * cp + iv * gv;
            float hnv = ov * ftanh(cn);
            cbuf[off] = cn;
            hcur[off] = f2bf(hnv);
            if (hT) hT[off] = hnv;
        }
    }
}

// ---------------- host ----------------
extern "C" void kernel_launch(void* const* d_in, const int* in_sizes, int n_in,
                              void* d_out, int out_size, void* d_ws, size_t ws_size,
                              hipStream_t stream) {
    const float* input = (const float*)d_in[0];
    const float* h0    = (const float*)d_in[1];
    const float* c0    = (const float*)d_in[2];
    const float* w_ih  = (const float*)d_in[3];
    const float* w_hh  = (const float*)d_in[4];
    const float* b_ih  = (const float*)d_in[5];
    const float* b_hh  = (const float*)d_in[6];

    float* ys = (float*)d_out;                    // [256][64][2048]
    float* hT = ys + (size_t)Tn * Bn * Hn;        // [64][2048]
    float* cT = hT + (size_t)Bn * Hn;             // [64][2048]

    char* wsb = (char*)d_ws;

    // persistent-path ws layout
    unsigned short* Xb  = (unsigned short*)wsb;                     // 16 MiB
    unsigned short* hp0 = (unsigned short*)(wsb + 16777216);        // 256 KiB (blocked)
    unsigned short* hp1 = (unsigned short*)(wsb + 17039360);        // 256 KiB
    float* biasP        = (float*)(wsb + 17301504);                 // 32 KiB
    unsigned* bar       = (unsigned*)(wsb + 17334272);              // 1.25 KiB
    const size_t coop_need = 17334272 + 320 * 4;

    bool coop_ok = (ws_size >= coop_need);
    if (coop_ok) {
        (void)hipFuncSetAttribute((const void*)lstm_persist,
                                  hipFuncAttributeMaxDynamicSharedMemorySize, 163840);
        // exact prologue coverage: n_x/4 + n_h/4 + n_b/4 + 320 barrier words
        const int prol_items = Tn * Bn * Xn / 4 + Bn * Hn / 4 + Gn / 4 + 320;  // 2,132,288
        const int prol_blocks = (prol_items + 255) / 256;                      // 8330
        prologue_coop<<<dim3(prol_blocks), dim3(256), 0, stream>>>(
            input, h0, b_ih, b_hh, Xb, hp0, biasP, bar);
        lstm_persist<<<dim3(NWG), dim3(320), 163840, stream>>>(
            Xb, biasP, c0, hp0, hp1, w_hh, w_ih, ys, hT, cT, bar);
        if (hipGetLastError() != hipSuccess) coop_ok = false;
    }
    if (coop_ok) return;

    // ---------------- fallback: round-1 step-kernel path ----------------
    float* cbuf = cT;  // c_T slot doubles as live c
    const size_t off_whh  = 0;
    const size_t off_wih  = off_whh + (size_t)Gn * Hn * 2;
    const size_t off_x    = off_wih + (size_t)Gn * Xn * 2;
    const size_t off_bias = off_x + (size_t)Tn * Bn * Xn * 2;
    const size_t off_h0   = off_bias + (size_t)Gn * 4;
    const size_t off_h1   = off_h0 + (size_t)Bn * Hn * 2;

    unsigned short* hbf[2] = {(unsigned short*)(wsb + off_h0), (unsigned short*)(wsb + off_h1)};
    unsigned short* Whh = (unsigned short*)(wsb + off_whh);
    unsigned short* Wih = (unsigned short*)(wsb + off_wih);
    unsigned short* Xf  = (unsigned short*)(wsb + off_x);
    float* bias = (float*)(wsb + off_bias);
    convert_full<<<dim3(28936), dim3(256), 0, stream>>>(
        w_hh, w_ih, input, b_ih, b_hh, h0, c0, Whh, Wih, Xf, bias, hbf[0], cbuf);
    for (int t = 0; t < Tn; ++t) {
        lstm_step<<<dim3(320), dim3(64), 0, stream>>>(
            Whh, Wih, Xf + (size_t)t * Bn * Xn, bias,
            hbf[t & 1], hbf[(t + 1) & 1], cbuf,
            t ? ys + (size_t)(t - 1) * Bn * Hn : nullptr,
            (t == Tn - 1) ? hT : nullptr);
    }
    softmax_final<<<dim3(Bn), dim3(64), 0, stream>>>(hbf[Tn & 1], ys + (size_t)(Tn - 1) * Bn * Hn);
}

// Round 5
// 4014.190 us; speedup vs baseline: 2.3654x; 1.0671x over previous
//
#include <hip/hip_runtime.h>

#define Tn 256
#define Bn 64
#define Xn 512
#define Hn 2048
#define Gn 8192  // 4*Hn
#define NWG 256

typedef short bf16x8 __attribute__((ext_vector_type(8)));
typedef float f32x4 __attribute__((ext_vector_type(4)));

static __device__ __forceinline__ unsigned short f2bf(float f) {
    unsigned int u = __builtin_bit_cast(unsigned int, f);
    u += 0x7fffu + ((u >> 16) & 1u);
    return (unsigned short)(u >> 16);
}
static __device__ __forceinline__ float bf2f(unsigned short s) {
    unsigned int u = ((unsigned int)s) << 16;
    return __builtin_bit_cast(float, u);
}
static __device__ __forceinline__ void cvt4(const float* __restrict__ s,
                                            unsigned short* __restrict__ d, int i) {
    float4 v = ((const float4*)s)[i];
    ushort4 o;
    o.x = f2bf(v.x); o.y = f2bf(v.y); o.z = f2bf(v.z); o.w = f2bf(v.w);
    ((ushort4*)d)[i] = o;
}
static __device__ __forceinline__ float sigm(float x) {
    return 1.f / (1.f + __expf(-x));
}
static __device__ __forceinline__ float ftanh(float x) {
    float e = __expf(2.f * x);
    return (e - 1.f) / (e + 1.f);
}

// ---------------- grid barrier (sharded arrive, gen poll) ----------------
static __device__ __forceinline__ void bar_wait(unsigned* bar, unsigned t) {
    if (t) {
        while (__hip_atomic_load(bar + 288, __ATOMIC_RELAXED, __HIP_MEMORY_SCOPE_AGENT) < t)
            __builtin_amdgcn_s_sleep(2);
    }
    __builtin_amdgcn_fence(__ATOMIC_ACQUIRE, "agent");
}
static __device__ __forceinline__ void bar_arrive(unsigned* bar, int wg, unsigned t) {
    __builtin_amdgcn_fence(__ATOMIC_RELEASE, "agent");
    unsigned* shard = bar + (wg >> 5) * 32;
    unsigned n = __hip_atomic_fetch_add(shard, 1u, __ATOMIC_RELAXED, __HIP_MEMORY_SCOPE_AGENT);
    if (n == 31u) {
        __hip_atomic_store(shard, 0u, __ATOMIC_RELAXED, __HIP_MEMORY_SCOPE_AGENT);
        unsigned m = __hip_atomic_fetch_add(bar + 256, 1u, __ATOMIC_RELAXED, __HIP_MEMORY_SCOPE_AGENT);
        if (m == 7u) {
            __hip_atomic_store(bar + 256, 0u, __ATOMIC_RELAXED, __HIP_MEMORY_SCOPE_AGENT);
            __hip_atomic_store(bar + 288, t + 1u, __ATOMIC_RELEASE, __HIP_MEMORY_SCOPE_AGENT);
        }
    }
}

// blocked h layout: elem(row,unit) at ((unit>>3)*64 + row)*8 + (unit&7)
static __device__ __forceinline__ void softmax_row_blocked(const unsigned short* __restrict__ hb,
                                                           int row, float* __restrict__ yr, int lane) {
    float v[32];
    float m = -1e30f;
    #pragma unroll
    for (int i = 0; i < 32; ++i) {
        int unit = (i << 6) + lane;
        v[i] = bf2f(hb[(((unit >> 3) << 6) + row) * 8 + (unit & 7)]);
        m = fmaxf(m, v[i]);
    }
    #pragma unroll
    for (int off = 32; off; off >>= 1) m = fmaxf(m, __shfl_xor(m, off));
    float s = 0.f;
    #pragma unroll
    for (int i = 0; i < 32; ++i) { v[i] = __expf(v[i] - m); s += v[i]; }
    #pragma unroll
    for (int off = 32; off; off >>= 1) s += __shfl_xor(s, off);
    float inv = 1.f / s;
    #pragma unroll
    for (int i = 0; i < 32; ++i) yr[lane + (i << 6)] = v[i] * inv;
}

// ---------------- prologue (new path): Xb cvt, Wih frag-layout, h0 blocked, bias, bar ----------------
__global__ void prologue2(const float* __restrict__ x, const float* __restrict__ h0,
                          const float* __restrict__ b_ih, const float* __restrict__ b_hh,
                          const float* __restrict__ w_ih,
                          unsigned short* __restrict__ Xb, unsigned short* __restrict__ XFrag,
                          unsigned short* __restrict__ hb0, float* __restrict__ bias,
                          unsigned* __restrict__ bar)
{
    int i = blockIdx.x * blockDim.x + threadIdx.x;
    const int n_x  = Tn * Bn * Xn / 4;  // 2097152
    const int n_xf = Gn * Xn / 4;       // 1048576
    const int n_h  = Bn * Hn / 4;       // 32768
    const int n_b  = Gn / 4;            // 2048
    if (i < n_x) { cvt4(x, Xb, i); return; }
    i -= n_x;
    if (i < n_xf) {
        // Wih -> per-WG B-fragment layout (32 KB per WG)
        int wg = i >> 12, r = i & 4095;
        int c = r >> 7, k = (r & 127) * 4;
        int g = c >> 3, u = c & 7;
        float4 v = *(const float4*)(w_ih + (size_t)(g * Hn + wg * 8 + u) * Xn + k);
        ushort4 o;
        o.x = f2bf(v.x); o.y = f2bf(v.y); o.z = f2bf(v.z); o.w = f2bf(v.w);
        int ct = c >> 4, kk = k >> 5, l = ((k >> 3) & 3) * 16 + (c & 15);
        *(ushort4*)((char*)XFrag + (size_t)wg * 32768 + (size_t)((ct * 16 + kk) * 64 + l) * 16 + (k & 7) * 2) = o;
        return;
    }
    i -= n_xf;
    if (i < n_h) {
        int flat = i * 4;
        int row = flat >> 11, unit0 = flat & 2047;
        float4 v = ((const float4*)h0)[i];
        ushort4 o;
        o.x = f2bf(v.x); o.y = f2bf(v.y); o.z = f2bf(v.z); o.w = f2bf(v.w);
        int dst = (((unit0 >> 3) << 6) + row) * 8 + (unit0 & 7);
        *(ushort4*)(hb0 + dst) = o;
        return;
    }
    i -= n_h;
    if (i < n_b) {
        float4 a = ((const float4*)b_ih)[i];
        float4 b = ((const float4*)b_hh)[i];
        ((float4*)bias)[i] = make_float4(a.x + b.x, a.y + b.y, a.z + b.z, a.w + b.w);
        return;
    }
    i -= n_b;
    if (i < 320) bar[i] = 0u;
}

#define MFMA2() \
    acc0 = __builtin_amdgcn_mfma_f32_16x16x32_bf16(a, b0, acc0, 0, 0, 0); \
    acc1 = __builtin_amdgcn_mfma_f32_16x16x32_bf16(a, b1, acc1, 0, 0, 0);

// ---------------- persistent LSTM, 8 waves, K-split ----------------
// waves: w = tid>>6; kh = w>>2 (K-half), rblk = w&3 (16-row block)
// LDS: [0,131072) Whh B-frags; [131072,139264) partial-sum RED; [139264,139296) softmax RED2
__global__ __launch_bounds__(512, 1) void lstm_persist2(
    const unsigned short* __restrict__ Xb, const unsigned short* __restrict__ XFrag,
    const float* __restrict__ bias, const float* __restrict__ c0,
    unsigned short* __restrict__ hb0, unsigned short* __restrict__ hb1,
    const float* __restrict__ w_hh,
    float* __restrict__ ys, float* __restrict__ hT, float* __restrict__ cT,
    unsigned* __restrict__ bar)
{
    extern __shared__ char smem[];
    const unsigned short* LW = (const unsigned short*)smem;
    float* RED  = (float*)(smem + 131072);
    float* RED2 = (float*)(smem + 139264);

    const int wg  = blockIdx.x;
    const int tid = threadIdx.x;
    const int U0  = wg * 8;

    // stage Whh slice -> LDS B-fragments (all 8 waves help)
    for (int i = tid; i < 32 * 512; i += 512) {
        int c = i >> 9, k = (i & 511) * 4;
        int g = c >> 3, u = c & 7;
        float4 v = *(const float4*)(w_hh + (size_t)(g * Hn + U0 + u) * Hn + k);
        ushort4 o;
        o.x = f2bf(v.x); o.y = f2bf(v.y); o.z = f2bf(v.z); o.w = f2bf(v.w);
        int ct = c >> 4, kk = k >> 5, l = ((k >> 3) & 3) * 16 + (c & 15);
        *(ushort4*)(smem + ((size_t)((ct * 64 + kk) * 64 + l) * 16 + (k & 7) * 2)) = o;
    }
    __syncthreads();

    const int w = tid >> 6, l = tid & 63;
    const int lm = l & 15, lh = l >> 4;
    const int kh = w >> 2, rblk = w & 3, rb = rblk * 16;
    const int kk0 = kh * 32;   // h-part K-chunk base (32 chunks of K=32)
    const int kx0 = kh * 8;    // x-part K-chunk base (8 chunks of K=32)

    const int u  = lm & 7;
    const bool hi = (lm & 8) != 0;
    const int r0g = rb + 4 * lh + (hi ? 2 : 0);

    float bi = 0.f, bf_ = 0.f, bg = 0.f, bo = 0.f, cs0 = 0.f, cs1 = 0.f;
    if (kh == 0) {
        bi  = bias[0 * Hn + U0 + u];
        bf_ = bias[1 * Hn + U0 + u];
        bg  = bias[2 * Hn + U0 + u];
        bo  = bias[3 * Hn + U0 + u];
        cs0 = c0[(size_t)r0g * Hn + U0 + u];
        cs1 = c0[(size_t)(r0g + 1) * Hn + U0 + u];
    }

    const char* xfb = (const char*)XFrag + (size_t)wg * 32768;

    for (int t = 0; t < Tn; ++t) {
        const unsigned short* hb = (t & 1) ? hb1 : hb0;
        unsigned short* hn = (t & 1) ? hb0 : hb1;

        f32x4 acc0 = {0.f, 0.f, 0.f, 0.f}, acc1 = {0.f, 0.f, 0.f, 0.f};

        // ---- x-part (this wave's K-quarter of 512): overlaps barrier stragglers ----
        {
            const unsigned short* xa = Xb + (size_t)(t * 64 + rb + lm) * Xn + lh * 8;
            bf16x8 aP[4];
            #pragma unroll
            for (int j = 0; j < 4; ++j) aP[j] = *(const bf16x8*)(xa + (kx0 + j) * 32);
            #pragma unroll 4
            for (int kkl = 0; kkl < 8; ++kkl) {
                bf16x8 a = aP[kkl & 3];
                if (kkl < 4) aP[kkl & 3] = *(const bf16x8*)(xa + (kx0 + kkl + 4) * 32);
                bf16x8 b0 = *(const bf16x8*)(xfb + ((size_t)((0 * 16 + kx0 + kkl) * 64 + l) << 4));
                bf16x8 b1 = *(const bf16x8*)(xfb + ((size_t)((1 * 16 + kx0 + kkl) * 64 + l) << 4));
                MFMA2();
            }
        }

        if (tid == 0) bar_wait(bar, (unsigned)t);
        __syncthreads();

        // ---- h-part (this wave's K-half of 2048) ----
        {
            const unsigned short* ha = hb + (size_t)(rb + lm) * 8;
            bf16x8 aP[4];
            #pragma unroll
            for (int j = 0; j < 4; ++j)
                aP[j] = *(const bf16x8*)(ha + (size_t)(((kk0 + j) * 4 + lh) << 6) * 8);
            #pragma unroll 4
            for (int kkl = 0; kkl < 32; ++kkl) {
                bf16x8 a = aP[kkl & 3];
                if (kkl < 28)
                    aP[kkl & 3] = *(const bf16x8*)(ha + (size_t)(((kk0 + kkl + 4) * 4 + lh) << 6) * 8);
                bf16x8 b0 = *(const bf16x8*)(LW + ((size_t)((0 * 64 + kk0 + kkl) * 64 + l) << 3));
                bf16x8 b1 = *(const bf16x8*)(LW + ((size_t)((1 * 64 + kk0 + kkl) * 64 + l) << 3));
                MFMA2();
            }
        }

        const bool do_sm = (kh == 1) && (wg < Bn) && (t > 0);
        float sv[8];
        if (kh == 1) {
            // dump partial sums for waves 0-3 to combine
            int idx = (rblk * 64 + l) * 8;
            *(f32x4*)(RED + idx)     = acc0;
            *(f32x4*)(RED + idx + 4) = acc1;
            if (do_sm) {
                // softmax(h_t) phase A: 4 waves split the 2048-unit row (row = wg)
                int row = wg;
                float m = -1e30f;
                #pragma unroll
                for (int j = 0; j < 8; ++j) {
                    int uu = rblk * 512 + j * 64 + l;
                    sv[j] = bf2f(hb[(size_t)(uu >> 3) * 512 + row * 8 + (uu & 7)]);
                    m = fmaxf(m, sv[j]);
                }
                #pragma unroll
                for (int off = 32; off; off >>= 1) m = fmaxf(m, __shfl_xor(m, off));
                float s = 0.f;
                #pragma unroll
                for (int j = 0; j < 8; ++j) s += __expf(sv[j] - m);
                #pragma unroll
                for (int off = 32; off; off >>= 1) s += __shfl_xor(s, off);
                if (l == 0) { RED2[rblk * 2] = m; RED2[rblk * 2 + 1] = s; }
            }
        }
        __syncthreads();

        if (kh == 0) {
            // combine K-halves, then the cell
            int idx = (rblk * 64 + l) * 8;
            acc0 += *(const f32x4*)(RED + idx);
            acc1 += *(const f32x4*)(RED + idx + 4);
            f32x4 s0, s1;
            #pragma unroll
            for (int r = 0; r < 4; ++r) { s0[r] = __shfl_xor(acc0[r], 8); s1[r] = __shfl_xor(acc1[r], 8); }
            #pragma unroll
            for (int j = 0; j < 2; ++j) {
                int r = (hi ? 2 : 0) + j;
                float gi = (hi ? s0[r] : acc0[r]) + bi;
                float gf = (hi ? acc0[r] : s0[r]) + bf_;
                float gg = (hi ? s1[r] : acc1[r]) + bg;
                float go = (hi ? acc1[r] : s1[r]) + bo;
                float iv = sigm(gi), fv = sigm(gf), gv = ftanh(gg), ov = sigm(go);
                float cc = j ? cs1 : cs0;
                float cn = fv * cc + iv * gv;
                float hv = ov * ftanh(cn);
                if (j) cs1 = cn; else cs0 = cn;
                int rowg = r0g + j;
                hn[(size_t)wg * 512 + rowg * 8 + u] = f2bf(hv);
                if (t == Tn - 1) {
                    size_t off = (size_t)rowg * Hn + U0 + u;
                    hT[off] = hv;
                    cT[off] = cn;
                }
            }
        } else if (do_sm) {
            // softmax phase B: combine 4 wave-partials, write ys[t-1]
            float m0 = RED2[0], sA = RED2[1], m1 = RED2[2], sB = RED2[3];
            float m2 = RED2[4], sC = RED2[5], m3 = RED2[6], sD = RED2[7];
            float gm = fmaxf(fmaxf(m0, m1), fmaxf(m2, m3));
            float gs = sA * __expf(m0 - gm) + sB * __expf(m1 - gm) +
                       sC * __expf(m2 - gm) + sD * __expf(m3 - gm);
            float inv = 1.f / gs;
            float* yr = ys + ((size_t)(t - 1) * Bn + wg) * Hn + rblk * 512;
            #pragma unroll
            for (int j = 0; j < 8; ++j) yr[j * 64 + l] = __expf(sv[j] - gm) * inv;
        }

        __syncthreads();
        if (tid == 0) bar_arrive(bar, wg, (unsigned)t);
    }

    // ---- final softmax: h_T sits in hb0 (Tn even) ----
    if (tid == 0) bar_wait(bar, Tn);
    __syncthreads();
    {
        const bool act = (kh == 1) && (wg < Bn);
        float sv[8];
        if (act) {
            int row = wg;
            float m = -1e30f;
            #pragma unroll
            for (int j = 0; j < 8; ++j) {
                int uu = rblk * 512 + j * 64 + l;
                sv[j] = bf2f(hb0[(size_t)(uu >> 3) * 512 + row * 8 + (uu & 7)]);
                m = fmaxf(m, sv[j]);
            }
            #pragma unroll
            for (int off = 32; off; off >>= 1) m = fmaxf(m, __shfl_xor(m, off));
            float s = 0.f;
            #pragma unroll
            for (int j = 0; j < 8; ++j) s += __expf(sv[j] - m);
            #pragma unroll
            for (int off = 32; off; off >>= 1) s += __shfl_xor(s, off);
            if (l == 0) { RED2[rblk * 2] = m; RED2[rblk * 2 + 1] = s; }
        }
        __syncthreads();
        if (act) {
            float m0 = RED2[0], sA = RED2[1], m1 = RED2[2], sB = RED2[3];
            float m2 = RED2[4], sC = RED2[5], m3 = RED2[6], sD = RED2[7];
            float gm = fmaxf(fmaxf(m0, m1), fmaxf(m2, m3));
            float gs = sA * __expf(m0 - gm) + sB * __expf(m1 - gm) +
                       sC * __expf(m2 - gm) + sD * __expf(m3 - gm);
            float inv = 1.f / gs;
            float* yr = ys + ((size_t)(Tn - 1) * Bn + wg) * Hn + rblk * 512;
            #pragma unroll
            for (int j = 0; j < 8; ++j) yr[j * 64 + l] = __expf(sv[j] - gm) * inv;
        }
    }
}

// =======================================================================
// ---------------- round-4 fallback path (proven, 17.4 MB ws) ----------------
// =======================================================================
__global__ void prologue_coop(const float* __restrict__ x, const float* __restrict__ h0,
                              const float* __restrict__ b_ih, const float* __restrict__ b_hh,
                              unsigned short* __restrict__ Xb, unsigned short* __restrict__ hb0,
                              float* __restrict__ bias, unsigned* __restrict__ bar)
{
    int i = blockIdx.x * blockDim.x + threadIdx.x;
    const int n_x = Tn * Bn * Xn / 4;
    const int n_h = Bn * Hn / 4;
    const int n_b = Gn / 4;
    if (i < n_x) { cvt4(x, Xb, i); return; }
    i -= n_x;
    if (i < n_h) {
        int flat = i * 4;
        int row = flat >> 11, unit0 = flat & 2047;
        float4 v = ((const float4*)h0)[i];
        ushort4 o;
        o.x = f2bf(v.x); o.y = f2bf(v.y); o.z = f2bf(v.z); o.w = f2bf(v.w);
        int dst = (((unit0 >> 3) << 6) + row) * 8 + (unit0 & 7);
        *(ushort4*)(hb0 + dst) = o;
        return;
    }
    i -= n_h;
    if (i < n_b) {
        float4 a = ((const float4*)b_ih)[i];
        float4 b = ((const float4*)b_hh)[i];
        ((float4*)bias)[i] = make_float4(a.x + b.x, a.y + b.y, a.z + b.z, a.w + b.w);
        return;
    }
    i -= n_b;
    if (i < 320) bar[i] = 0u;
}

__global__ __launch_bounds__(320, 1) void lstm_persist(
    const unsigned short* __restrict__ Xb, const float* __restrict__ bias,
    const float* __restrict__ c0,
    unsigned short* __restrict__ hb0, unsigned short* __restrict__ hb1,
    const float* __restrict__ w_hh, const float* __restrict__ w_ih,
    float* __restrict__ ys, float* __restrict__ hT, float* __restrict__ cT,
    unsigned* __restrict__ bar)
{
    extern __shared__ char smem[];
    const unsigned short* LW = (const unsigned short*)smem;
    const unsigned short* LX = (const unsigned short*)(smem + 131072);

    const int wg  = blockIdx.x;
    const int tid = threadIdx.x;
    const int U0  = wg * 8;

    for (int i = tid; i < 32 * 512; i += 320) {
        int c = i >> 9, k = (i & 511) * 4;
        int g = c >> 3, u = c & 7;
        float4 v = *(const float4*)(w_hh + (size_t)(g * Hn + U0 + u) * Hn + k);
        ushort4 o;
        o.x = f2bf(v.x); o.y = f2bf(v.y); o.z = f2bf(v.z); o.w = f2bf(v.w);
        int ct = c >> 4, kk = k >> 5, l = ((k >> 3) & 3) * 16 + (c & 15);
        *(ushort4*)(smem + ((size_t)((ct * 64 + kk) * 64 + l) * 16 + (k & 7) * 2)) = o;
    }
    for (int i = tid; i < 32 * 128; i += 320) {
        int c = i >> 7, k = (i & 127) * 4;
        int g = c >> 3, u = c & 7;
        float4 v = *(const float4*)(w_ih + (size_t)(g * Hn + U0 + u) * Xn + k);
        ushort4 o;
        o.x = f2bf(v.x); o.y = f2bf(v.y); o.z = f2bf(v.z); o.w = f2bf(v.w);
        int ct = c >> 4, kk = k >> 5, l = ((k >> 3) & 3) * 16 + (c & 15);
        *(ushort4*)(smem + (131072 + (size_t)((ct * 16 + kk) * 64 + l) * 16 + (k & 7) * 2)) = o;
    }
    __syncthreads();

    const int w = tid >> 6, l = tid & 63;
    const int lm = l & 15, lh = l >> 4;
    const int row0 = w * 16;
    const int u  = lm & 7;
    const bool hi = (lm & 8) != 0;
    const int r0g = row0 + 4 * lh + (hi ? 2 : 0);

    float bi = 0.f, bf_ = 0.f, bg = 0.f, bo = 0.f, cs0 = 0.f, cs1 = 0.f;
    if (w < 4) {
        bi  = bias[0 * Hn + U0 + u];
        bf_ = bias[1 * Hn + U0 + u];
        bg  = bias[2 * Hn + U0 + u];
        bo  = bias[3 * Hn + U0 + u];
        cs0 = c0[(size_t)r0g * Hn + U0 + u];
        cs1 = c0[(size_t)(r0g + 1) * Hn + U0 + u];
    }

    for (int t = 0; t < Tn; ++t) {
        const unsigned short* hb = (t & 1) ? hb1 : hb0;
        unsigned short* hn = (t & 1) ? hb0 : hb1;
        f32x4 acc0 = {0.f, 0.f, 0.f, 0.f}, acc1 = {0.f, 0.f, 0.f, 0.f};

        if (w < 4) {
            const unsigned short* xa = Xb + ((size_t)(t * 64 + row0 + lm) * Xn) + lh * 8;
            bf16x8 aP[4];
            #pragma unroll
            for (int j = 0; j < 4; ++j) aP[j] = *(const bf16x8*)(xa + j * 32);
            #pragma unroll 4
            for (int kk = 0; kk < 16; ++kk) {
                bf16x8 a = aP[kk & 3];
                if (kk < 12) aP[kk & 3] = *(const bf16x8*)(xa + (kk + 4) * 32);
                bf16x8 b0 = *(const bf16x8*)(LX + ((size_t)((0 * 16 + kk) * 64 + l) << 3));
                bf16x8 b1 = *(const bf16x8*)(LX + ((size_t)((1 * 16 + kk) * 64 + l) << 3));
                MFMA2();
            }
        }

        if (tid == 0) bar_wait(bar, (unsigned)t);
        __syncthreads();

        if (w < 4) {
            const unsigned short* ha = hb + (size_t)(row0 + lm) * 8;
            bf16x8 aP[4];
            #pragma unroll
            for (int j = 0; j < 4; ++j)
                aP[j] = *(const bf16x8*)(ha + (size_t)((j * 4 + lh) << 6) * 8);
            #pragma unroll 4
            for (int kk = 0; kk < 64; ++kk) {
                bf16x8 a = aP[kk & 3];
                if (kk < 60)
                    aP[kk & 3] = *(const bf16x8*)(ha + (size_t)((((kk + 4) * 4 + lh)) << 6) * 8);
                bf16x8 b0 = *(const bf16x8*)(LW + ((size_t)((0 * 64 + kk) * 64 + l) << 3));
                bf16x8 b1 = *(const bf16x8*)(LW + ((size_t)((1 * 64 + kk) * 64 + l) << 3));
                MFMA2();
            }
            f32x4 s0, s1;
            #pragma unroll
            for (int r = 0; r < 4; ++r) { s0[r] = __shfl_xor(acc0[r], 8); s1[r] = __shfl_xor(acc1[r], 8); }
            #pragma unroll
            for (int j = 0; j < 2; ++j) {
                int r = (hi ? 2 : 0) + j;
                float gi = (hi ? s0[r] : acc0[r]) + bi;
                float gf = (hi ? acc0[r] : s0[r]) + bf_;
                float gg = (hi ? s1[r] : acc1[r]) + bg;
                float go = (hi ? acc1[r] : s1[r]) + bo;
                float iv = sigm(gi), fv = sigm(gf), gv = ftanh(gg), ov = sigm(go);
                float cc = j ? cs1 : cs0;
                float cn = fv * cc + iv * gv;
                float hv = ov * ftanh(cn);
                if (j) cs1 = cn; else cs0 = cn;
                int rowg = r0g + j;
                hn[(size_t)wg * 512 + rowg * 8 + u] = f2bf(hv);
                if (t == Tn - 1) {
                    size_t off = (size_t)rowg * Hn + U0 + u;
                    hT[off] = hv;
                    cT[off] = cn;
                }
            }
        } else if (wg < 64 && t > 0) {
            softmax_row_blocked(hb, wg, ys + ((size_t)(t - 1) * Bn + wg) * Hn, l);
        }

        __syncthreads();
        if (tid == 0) bar_arrive(bar, wg, (unsigned)t);
    }

    if (tid == 0) bar_wait(bar, Tn);
    __syncthreads();
    if (w == 4 && wg < 64)
        softmax_row_blocked(hb0, wg, ys + ((size_t)(Tn - 1) * Bn + wg) * Hn, l);
}

// ---------------- host ----------------
extern "C" void kernel_launch(void* const* d_in, const int* in_sizes, int n_in,
                              void* d_out, int out_size, void* d_ws, size_t ws_size,
                              hipStream_t stream) {
    const float* input = (const float*)d_in[0];
    const float* h0    = (const float*)d_in[1];
    const float* c0    = (const float*)d_in[2];
    const float* w_ih  = (const float*)d_in[3];
    const float* w_hh  = (const float*)d_in[4];
    const float* b_ih  = (const float*)d_in[5];
    const float* b_hh  = (const float*)d_in[6];

    float* ys = (float*)d_out;
    float* hT = ys + (size_t)Tn * Bn * Hn;
    float* cT = hT + (size_t)Bn * Hn;

    char* wsb = (char*)d_ws;

    // new-path ws layout
    unsigned short* Xb2 = (unsigned short*)wsb;                   // 16,777,216
    unsigned short* XF  = (unsigned short*)(wsb + 16777216);      //  8,388,608
    unsigned short* hq0 = (unsigned short*)(wsb + 25165824);      //    262,144
    unsigned short* hq1 = (unsigned short*)(wsb + 25427968);      //    262,144
    float* bias2        = (float*)(wsb + 25690112);               //     32,768
    unsigned* bar2      = (unsigned*)(wsb + 25722880);            //      1,280
    const size_t need2  = 25724160;

    if (ws_size >= need2) {
        (void)hipFuncSetAttribute((const void*)lstm_persist2,
                                  hipFuncAttributeMaxDynamicSharedMemorySize, 139328);
        const int prol_items = Tn * Bn * Xn / 4 + Gn * Xn / 4 + Bn * Hn / 4 + Gn / 4 + 320;
        const int prol_blocks = (prol_items + 255) / 256;
        prologue2<<<dim3(prol_blocks), dim3(256), 0, stream>>>(
            input, h0, b_ih, b_hh, w_ih, Xb2, XF, hq0, bias2, bar2);
        lstm_persist2<<<dim3(NWG), dim3(512), 139328, stream>>>(
            Xb2, XF, bias2, c0, hq0, hq1, w_hh, ys, hT, cT, bar2);
        return;
    }

    // fallback: round-4 layout + kernel
    unsigned short* Xb  = (unsigned short*)wsb;
    unsigned short* hp0 = (unsigned short*)(wsb + 16777216);
    unsigned short* hp1 = (unsigned short*)(wsb + 17039360);
    float* biasP        = (float*)(wsb + 17301504);
    unsigned* bar       = (unsigned*)(wsb + 17334272);
    (void)hipFuncSetAttribute((const void*)lstm_persist,
                              hipFuncAttributeMaxDynamicSharedMemorySize, 163840);
    const int prol_items = Tn * Bn * Xn / 4 + Bn * Hn / 4 + Gn / 4 + 320;
    const int prol_blocks = (prol_items + 255) / 256;
    prologue_coop<<<dim3(prol_blocks), dim3(256), 0, stream>>>(
        input, h0, b_ih, b_hh, Xb, hp0, biasP, bar);
    lstm_persist<<<dim3(NWG), dim3(320), 163840, stream>>>(
        Xb, biasP, c0, hp0, hp1, w_hh, w_ih, ys, hT, cT, bar);
}

// Round 6
// 2131.341 us; speedup vs baseline: 4.4550x; 1.8834x over previous
//
#include <hip/hip_runtime.h>

#define Tn 256
#define Bn 64
#define Xn 512
#define Hn 2048
#define Gn 8192  // 4*Hn
#define NWG 256

typedef short bf16x8 __attribute__((ext_vector_type(8)));
typedef float f32x4 __attribute__((ext_vector_type(4)));
typedef unsigned uint32x4 __attribute__((ext_vector_type(4)));

#define AL(p)    __hip_atomic_load((p), __ATOMIC_RELAXED, __HIP_MEMORY_SCOPE_AGENT)
#define AS(p, v) __hip_atomic_store((p), (v), __ATOMIC_RELAXED, __HIP_MEMORY_SCOPE_AGENT)

static __device__ __forceinline__ unsigned short f2bf(float f) {
    unsigned int u = __builtin_bit_cast(unsigned int, f);
    u += 0x7fffu + ((u >> 16) & 1u);
    return (unsigned short)(u >> 16);
}
static __device__ __forceinline__ float bf2f(unsigned short s) {
    unsigned int u = ((unsigned int)s) << 16;
    return __builtin_bit_cast(float, u);
}
static __device__ __forceinline__ void cvt4(const float* __restrict__ s,
                                            unsigned short* __restrict__ d, int i) {
    float4 v = ((const float4*)s)[i];
    ushort4 o;
    o.x = f2bf(v.x); o.y = f2bf(v.y); o.z = f2bf(v.z); o.w = f2bf(v.w);
    ((ushort4*)d)[i] = o;
}
static __device__ __forceinline__ float sigm(float x) {
    return 1.f / (1.f + __expf(-x));
}
static __device__ __forceinline__ float ftanh(float x) {
    float e = __expf(2.f * x);
    return (e - 1.f) / (e + 1.f);
}

// h buffer offset within the ring (bytes). RING: 257 buffers, index permuted
// by *97 mod 257 so successive steps are not address-adjacent (defeats any
// L2 stride prefetch from running ahead into a not-yet-written buffer).
template <int RING>
static __device__ __forceinline__ size_t hoff(int t) {
    if constexpr (RING) return (size_t)((t * 97) % 257) * 262144;
    else                return (size_t)(t & 1) * 262144;
}

// 16B h fragment load. RING: plain cached load (fresh address each step).
// BYPASS: 4 relaxed agent-scope atomic dword loads (LLC-coherent, skip stale L2).
template <int RING>
static __device__ __forceinline__ bf16x8 ldh(const unsigned short* p) {
    if constexpr (RING) {
        return *(const bf16x8*)p;
    } else {
        unsigned* q = (unsigned*)p;
        uint32x4 v;
        v[0] = AL(q + 0); v[1] = AL(q + 1); v[2] = AL(q + 2); v[3] = AL(q + 3);
        return __builtin_bit_cast(bf16x8, v);
    }
}
// scalar h element load (softmax path); idx in ushort units, buffer 4B-aligned
template <int RING>
static __device__ __forceinline__ float ldh1(const unsigned short* hb, int idx) {
    if constexpr (RING) {
        return bf2f(hb[idx]);
    } else {
        unsigned d = AL((unsigned*)(hb + (idx & ~1)));
        return bf2f((idx & 1) ? (unsigned short)(d >> 16) : (unsigned short)(d & 0xffffu));
    }
}

// ---------------- flag barrier ----------------
// flags[wg] = (last completed step + 1). Wave 0 polls 4 flags/lane.
static __device__ __forceinline__ void flags_wait(unsigned* flags, unsigned t, int l) {
    if (!t) return;
    unsigned* p = flags + l * 4;
    for (;;) {
        unsigned a0 = AL(p + 0), a1 = AL(p + 1), a2 = AL(p + 2), a3 = AL(p + 3);
        bool ok = (a0 >= t) & (a1 >= t) & (a2 >= t) & (a3 >= t);
        if (__all(ok)) break;
        __builtin_amdgcn_s_sleep(1);
    }
}

// ---------------- prologue ----------------
__global__ void prologue3(const float* __restrict__ x, const float* __restrict__ h0,
                          const float* __restrict__ b_ih, const float* __restrict__ b_hh,
                          const float* __restrict__ w_ih,
                          unsigned short* __restrict__ Xb, unsigned short* __restrict__ XFrag,
                          unsigned short* __restrict__ hb0, float* __restrict__ bias,
                          unsigned* __restrict__ flags)
{
    int i = blockIdx.x * blockDim.x + threadIdx.x;
    const int n_x  = Tn * Bn * Xn / 4;  // 2097152
    const int n_xf = Gn * Xn / 4;       // 1048576
    const int n_h  = Bn * Hn / 4;       // 32768
    const int n_b  = Gn / 4;            // 2048
    if (i < n_x) { cvt4(x, Xb, i); return; }
    i -= n_x;
    if (i < n_xf) {
        // Wih -> per-WG B-fragment layout (32 KB per WG)
        int wg = i >> 12, r = i & 4095;
        int c = r >> 7, k = (r & 127) * 4;
        int g = c >> 3, u = c & 7;
        float4 v = *(const float4*)(w_ih + (size_t)(g * Hn + wg * 8 + u) * Xn + k);
        ushort4 o;
        o.x = f2bf(v.x); o.y = f2bf(v.y); o.z = f2bf(v.z); o.w = f2bf(v.w);
        int ct = c >> 4, kk = k >> 5, l = ((k >> 3) & 3) * 16 + (c & 15);
        *(ushort4*)((char*)XFrag + (size_t)wg * 32768 + (size_t)((ct * 16 + kk) * 64 + l) * 16 + (k & 7) * 2) = o;
        return;
    }
    i -= n_xf;
    if (i < n_h) {
        // h0 -> blocked bf16 layout: elem(row,unit) at ((unit>>3)*64+row)*8+(unit&7)
        int flat = i * 4;
        int row = flat >> 11, unit0 = flat & 2047;
        float4 v = ((const float4*)h0)[i];
        ushort4 o;
        o.x = f2bf(v.x); o.y = f2bf(v.y); o.z = f2bf(v.z); o.w = f2bf(v.w);
        int dst = (((unit0 >> 3) << 6) + row) * 8 + (unit0 & 7);
        *(ushort4*)(hb0 + dst) = o;
        return;
    }
    i -= n_h;
    if (i < n_b) {
        float4 a = ((const float4*)b_ih)[i];
        float4 b = ((const float4*)b_hh)[i];
        ((float4*)bias)[i] = make_float4(a.x + b.x, a.y + b.y, a.z + b.z, a.w + b.w);
        return;
    }
    i -= n_b;
    if (i < 256) flags[i] = 0u;
}

#define MFMA2() \
    acc0 = __builtin_amdgcn_mfma_f32_16x16x32_bf16(a, b0, acc0, 0, 0, 0); \
    acc1 = __builtin_amdgcn_mfma_f32_16x16x32_bf16(a, b1, acc1, 0, 0, 0);

// ---------------- persistent LSTM, 8 waves, K-split, flag barrier ----------------
// waves: w = tid>>6; kh = w>>2 (K-half), rblk = w&3 (16-row block)
// LDS: [0,131072) Whh B-frags; [131072,139264) partial-sum RED; [139264,139296) RED2
template <int RING>
__global__ __launch_bounds__(512, 1) void lstm_persist3(
    const unsigned short* __restrict__ Xb, const unsigned short* __restrict__ XFrag,
    const float* __restrict__ bias, const float* __restrict__ c0,
    char* __restrict__ hbase, const float* __restrict__ w_hh,
    float* __restrict__ ys, float* __restrict__ hT, float* __restrict__ cT,
    unsigned* __restrict__ flags)
{
    extern __shared__ char smem[];
    const unsigned short* LW = (const unsigned short*)smem;
    float* RED  = (float*)(smem + 131072);
    float* RED2 = (float*)(smem + 139264);

    const int wg  = blockIdx.x;
    const int tid = threadIdx.x;
    const int U0  = wg * 8;

    // stage Whh slice -> LDS B-fragments (all 8 waves help)
    for (int i = tid; i < 32 * 512; i += 512) {
        int c = i >> 9, k = (i & 511) * 4;
        int g = c >> 3, u = c & 7;
        float4 v = *(const float4*)(w_hh + (size_t)(g * Hn + U0 + u) * Hn + k);
        ushort4 o;
        o.x = f2bf(v.x); o.y = f2bf(v.y); o.z = f2bf(v.z); o.w = f2bf(v.w);
        int ct = c >> 4, kk = k >> 5, l = ((k >> 3) & 3) * 16 + (c & 15);
        *(ushort4*)(smem + ((size_t)((ct * 64 + kk) * 64 + l) * 16 + (k & 7) * 2)) = o;
    }
    __syncthreads();

    const int w = tid >> 6, l = tid & 63;
    const int lm = l & 15, lh = l >> 4;
    const int kh = w >> 2, rblk = w & 3, rb = rblk * 16;
    const int kk0 = kh * 32;   // h-part K-chunk base (32 chunks of K=32)
    const int kx0 = kh * 8;    // x-part K-chunk base

    const int u  = lm & 7;
    const bool hi = (lm & 8) != 0;
    const int r0g = rb + 4 * lh + (hi ? 2 : 0);

    float bi = 0.f, bf_ = 0.f, bg = 0.f, bo = 0.f, cs0 = 0.f, cs1 = 0.f;
    if (kh == 0) {
        bi  = bias[0 * Hn + U0 + u];
        bf_ = bias[1 * Hn + U0 + u];
        bg  = bias[2 * Hn + U0 + u];
        bo  = bias[3 * Hn + U0 + u];
        cs0 = c0[(size_t)r0g * Hn + U0 + u];
        cs1 = c0[(size_t)(r0g + 1) * Hn + U0 + u];
    }

    const char* xfb = (const char*)XFrag + (size_t)wg * 32768;

    for (int t = 0; t < Tn; ++t) {
        const unsigned short* hb = (const unsigned short*)(hbase + hoff<RING>(t));
        unsigned short* hn = (unsigned short*)(hbase + hoff<RING>(t + 1));

        f32x4 acc0 = {0.f, 0.f, 0.f, 0.f}, acc1 = {0.f, 0.f, 0.f, 0.f};

        // ---- x-part (this wave's K-quarter of 512): before the flag wait ----
        {
            const unsigned short* xa = Xb + (size_t)(t * 64 + rb + lm) * Xn + lh * 8;
            bf16x8 aP[4];
            #pragma unroll
            for (int j = 0; j < 4; ++j) aP[j] = *(const bf16x8*)(xa + (kx0 + j) * 32);
            #pragma unroll 4
            for (int kkl = 0; kkl < 8; ++kkl) {
                bf16x8 a = aP[kkl & 3];
                if (kkl < 4) aP[kkl & 3] = *(const bf16x8*)(xa + (kx0 + kkl + 4) * 32);
                bf16x8 b0 = *(const bf16x8*)(xfb + ((size_t)((0 * 16 + kx0 + kkl) * 64 + l) << 4));
                bf16x8 b1 = *(const bf16x8*)(xfb + ((size_t)((1 * 16 + kx0 + kkl) * 64 + l) << 4));
                MFMA2();
            }
        }

        if (w == 0) flags_wait(flags, (unsigned)t, l);
        __syncthreads();

        // ---- h-part (this wave's K-half of 2048), depth-8 prefetch ----
        {
            const unsigned short* ha = hb + (size_t)(rb + lm) * 8;
            bf16x8 aP[8];
            #pragma unroll
            for (int j = 0; j < 8; ++j)
                aP[j] = ldh<RING>(ha + (size_t)((kk0 + j) * 4 + lh) * 512);
            #pragma unroll 8
            for (int kkl = 0; kkl < 32; ++kkl) {
                bf16x8 a = aP[kkl & 7];
                if (kkl < 24)
                    aP[kkl & 7] = ldh<RING>(ha + (size_t)((kk0 + kkl + 8) * 4 + lh) * 512);
                bf16x8 b0 = *(const bf16x8*)(LW + ((size_t)((0 * 64 + kk0 + kkl) * 64 + l) << 3));
                bf16x8 b1 = *(const bf16x8*)(LW + ((size_t)((1 * 64 + kk0 + kkl) * 64 + l) << 3));
                MFMA2();
            }
        }

        const bool do_sm = (kh == 1) && (wg < Bn) && (t > 0);
        float sv[8];
        if (kh == 1) {
            int idx = (rblk * 64 + l) * 8;
            *(f32x4*)(RED + idx)     = acc0;
            *(f32x4*)(RED + idx + 4) = acc1;
            if (do_sm) {
                // softmax phase A: 4 waves split the 2048-unit row (row = wg)
                int row = wg;
                float m = -1e30f;
                #pragma unroll
                for (int j = 0; j < 8; ++j) {
                    int uu = rblk * 512 + j * 64 + l;
                    sv[j] = ldh1<RING>(hb, (uu >> 3) * 512 + row * 8 + (uu & 7));
                    m = fmaxf(m, sv[j]);
                }
                #pragma unroll
                for (int off = 32; off; off >>= 1) m = fmaxf(m, __shfl_xor(m, off));
                float s = 0.f;
                #pragma unroll
                for (int j = 0; j < 8; ++j) s += __expf(sv[j] - m);
                #pragma unroll
                for (int off = 32; off; off >>= 1) s += __shfl_xor(s, off);
                if (l == 0) { RED2[rblk * 2] = m; RED2[rblk * 2 + 1] = s; }
            }
        }
        __syncthreads();

        if (kh == 0) {
            // combine K-halves, then the cell
            int idx = (rblk * 64 + l) * 8;
            acc0 += *(const f32x4*)(RED + idx);
            acc1 += *(const f32x4*)(RED + idx + 4);
            f32x4 s0, s1;
            #pragma unroll
            for (int r = 0; r < 4; ++r) { s0[r] = __shfl_xor(acc0[r], 8); s1[r] = __shfl_xor(acc1[r], 8); }
            #pragma unroll
            for (int j = 0; j < 2; ++j) {
                int r = (hi ? 2 : 0) + j;
                float gi = (hi ? s0[r] : acc0[r]) + bi;
                float gf = (hi ? acc0[r] : s0[r]) + bf_;
                float gg = (hi ? s1[r] : acc1[r]) + bg;
                float go = (hi ? acc1[r] : s1[r]) + bo;
                float iv = sigm(gi), fv = sigm(gf), gv = ftanh(gg), ov = sigm(go);
                float cc = j ? cs1 : cs0;
                float cn = fv * cc + iv * gv;
                float hv = ov * ftanh(cn);
                if (j) cs1 = cn; else cs0 = cn;
                int rowg = r0g + j;
                // pack lane-pair (u, u^1) -> one coherent dword store (write-through)
                unsigned short mybf = f2bf(hv);
                unsigned other = (unsigned)__shfl_xor((int)(unsigned)mybf, 1);
                if (!(u & 1)) {
                    unsigned pk = (unsigned)mybf | (other << 16);
                    AS((unsigned*)(hn + (size_t)wg * 512 + rowg * 8 + u), pk);
                }
                if (t == Tn - 1) {
                    size_t off = (size_t)rowg * Hn + U0 + u;
                    hT[off] = hv;
                    cT[off] = cn;
                }
            }
        }
        __syncthreads();   // drains all waves' h stores (implicit vmcnt(0))
        if (tid == 0) AS(flags + wg, (unsigned)(t + 1));

        if (do_sm) {
            // softmax phase B after the flag publish — off the critical path
            float m0 = RED2[0], sA = RED2[1], m1 = RED2[2], sB = RED2[3];
            float m2 = RED2[4], sC = RED2[5], m3 = RED2[6], sD = RED2[7];
            float gm = fmaxf(fmaxf(m0, m1), fmaxf(m2, m3));
            float gs = sA * __expf(m0 - gm) + sB * __expf(m1 - gm) +
                       sC * __expf(m2 - gm) + sD * __expf(m3 - gm);
            float inv = 1.f / gs;
            float* yr = ys + ((size_t)(t - 1) * Bn + wg) * Hn + rblk * 512;
            #pragma unroll
            for (int j = 0; j < 8; ++j) yr[j * 64 + l] = __expf(sv[j] - gm) * inv;
        }
    }

    // ---- final softmax: h(Tn) ----
    if (w == 0) flags_wait(flags, (unsigned)Tn, l);
    __syncthreads();
    {
        const unsigned short* hfin = (const unsigned short*)(hbase + hoff<RING>(Tn));
        const bool act = (kh == 1) && (wg < Bn);
        float sv[8];
        if (act) {
            int row = wg;
            float m = -1e30f;
            #pragma unroll
            for (int j = 0; j < 8; ++j) {
                int uu = rblk * 512 + j * 64 + l;
                sv[j] = ldh1<RING>(hfin, (uu >> 3) * 512 + row * 8 + (uu & 7));
                m = fmaxf(m, sv[j]);
            }
            #pragma unroll
            for (int off = 32; off; off >>= 1) m = fmaxf(m, __shfl_xor(m, off));
            float s = 0.f;
            #pragma unroll
            for (int j = 0; j < 8; ++j) s += __expf(sv[j] - m);
            #pragma unroll
            for (int off = 32; off; off >>= 1) s += __shfl_xor(s, off);
            if (l == 0) { RED2[rblk * 2] = m; RED2[rblk * 2 + 1] = s; }
        }
        __syncthreads();
        if (act) {
            float m0 = RED2[0], sA = RED2[1], m1 = RED2[2], sB = RED2[3];
            float m2 = RED2[4], sC = RED2[5], m3 = RED2[6], sD = RED2[7];
            float gm = fmaxf(fmaxf(m0, m1), fmaxf(m2, m3));
            float gs = sA * __expf(m0 - gm) + sB * __expf(m1 - gm) +
                       sC * __expf(m2 - gm) + sD * __expf(m3 - gm);
            float inv = 1.f / gs;
            float* yr = ys + ((size_t)(Tn - 1) * Bn + wg) * Hn + rblk * 512;
            #pragma unroll
            for (int j = 0; j < 8; ++j) yr[j * 64 + l] = __expf(sv[j] - gm) * inv;
        }
    }
}

// ---------------- host ----------------
extern "C" void kernel_launch(void* const* d_in, const int* in_sizes, int n_in,
                              void* d_out, int out_size, void* d_ws, size_t ws_size,
                              hipStream_t stream) {
    const float* input = (const float*)d_in[0];
    const float* h0    = (const float*)d_in[1];
    const float* c0    = (const float*)d_in[2];
    const float* w_ih  = (const float*)d_in[3];
    const float* w_hh  = (const float*)d_in[4];
    const float* b_ih  = (const float*)d_in[5];
    const float* b_hh  = (const float*)d_in[6];

    float* ys = (float*)d_out;                    // [256][64][2048]
    float* hT = ys + (size_t)Tn * Bn * Hn;        // [64][2048]
    float* cT = hT + (size_t)Bn * Hn;             // [64][2048]

    char* wsb = (char*)d_ws;
    // ws layout (both paths):
    unsigned short* Xb  = (unsigned short*)wsb;                  // 16,777,216
    unsigned short* XF  = (unsigned short*)(wsb + 16777216);     //  8,388,608
    float* bias         = (float*)(wsb + 25165824);              //     32,768
    unsigned* flags     = (unsigned*)(wsb + 25198592);           //      1,024
    char* hbase         = wsb + 25199616;                        // h buffers
    const size_t need_ring   = 25199616 + (size_t)257 * 262144;  // 92,570,624
    // bypass need = 25,199,616 + 524,288 = 25,723,904 (<= proven ws)

    const int prol_items = Tn * Bn * Xn / 4 + Gn * Xn / 4 + Bn * Hn / 4 + Gn / 4 + 256;
    const int prol_blocks = (prol_items + 255) / 256;
    prologue3<<<dim3(prol_blocks), dim3(256), 0, stream>>>(
        input, h0, b_ih, b_hh, w_ih, Xb, XF, (unsigned short*)hbase, bias, flags);

    if (ws_size >= need_ring) {
        (void)hipFuncSetAttribute((const void*)lstm_persist3<1>,
                                  hipFuncAttributeMaxDynamicSharedMemorySize, 139328);
        lstm_persist3<1><<<dim3(NWG), dim3(512), 139328, stream>>>(
            Xb, XF, bias, c0, hbase, w_hh, ys, hT, cT, flags);
    } else {
        (void)hipFuncSetAttribute((const void*)lstm_persist3<0>,
                                  hipFuncAttributeMaxDynamicSharedMemorySize, 139328);
        lstm_persist3<0><<<dim3(NWG), dim3(512), 139328, stream>>>(
            Xb, XF, bias, c0, hbase, w_hh, ys, hT, cT, flags);
    }
}